// Round 1
// baseline (314.697 us; speedup 1.0000x reference)
//
#include <hip/hip_runtime.h>

typedef short s8v __attribute__((ext_vector_type(8)));
typedef short s4v __attribute__((ext_vector_type(4)));
typedef float f4v __attribute__((ext_vector_type(4)));

#define MFMA16(a,b,c) __builtin_amdgcn_mfma_f32_16x16x32_bf16((a),(b),(c),0,0,0)

__device__ __forceinline__ unsigned short f2bf(float x) {
  union { float f; unsigned u; } v; v.f = x;
  unsigned r = v.u + 0x7FFFu + ((v.u >> 16) & 1u);   // RNE
  return (unsigned short)(r >> 16);
}

__device__ __forceinline__ float redmax16(float v) {
  v = fmaxf(v, __shfl_xor(v, 1));
  v = fmaxf(v, __shfl_xor(v, 2));
  v = fmaxf(v, __shfl_xor(v, 4));
  v = fmaxf(v, __shfl_xor(v, 8));
  return v;
}
__device__ __forceinline__ float redsum16(float v) {
  v += __shfl_xor(v, 1);
  v += __shfl_xor(v, 2);
  v += __shfl_xor(v, 4);
  v += __shfl_xor(v, 8);
  return v;
}

// Transpose weights to bf16: WT[m][n][k] = W_m[k][n]; Wq pre-scaled by 1/8 (exact).
__global__ void prep_wt(const float* __restrict__ Wk, const float* __restrict__ Wq,
                        const float* __restrict__ Wv, unsigned short* __restrict__ WT) {
  int i = blockIdx.x * 256 + threadIdx.x;
  if (i >= 64 * 64) return;
  int n = i >> 6, k = i & 63;
  WT[i]            = f2bf(Wk[k * 64 + n]);
  WT[4096 + i]     = f2bf(Wq[k * 64 + n] * 0.125f);
  WT[2 * 4096 + i] = f2bf(Wv[k * 64 + n]);
}

// One workgroup (4 waves) per batch element. Fused QKV-proj + causal flash attention.
// LDS: K [256][64] bf16 swz (32K) | V^T [64][256] bf16 swz (32K) | 4x 2K per-wave scratch.
__global__ __launch_bounds__(256, 2) void head_fused(
    const float* __restrict__ X, const unsigned short* __restrict__ WT,
    const float* __restrict__ bk, const float* __restrict__ bq,
    const float* __restrict__ bv, float* __restrict__ Out)
{
  __shared__ char lds[73728];
  char* Kl = lds;               // byte(row,col) = row*128 + col*2, ^((row&7)<<4)
  char* Vt = lds + 32768;       // byte(h,t)     = h*512  + t*2,   ^((h&7)<<4)
  const int tid  = threadIdx.x;
  const int wave = tid >> 6;
  const int lane = tid & 63;
  const int lrow = lane & 15;   // row/col-within-16 index
  const int lgrp = lane >> 4;   // 0..3
  char* scw = lds + 65536 + wave * 2048;   // per-wave scratch (Q bounce / P bounce)

  const float* Xb = X + (size_t)blockIdx.x * (256 * 64);
  float* Ob = Out + (size_t)blockIdx.x * (256 * 64);

  float biask[4], biasq[4], biasv[4];
#pragma unroll
  for (int nt = 0; nt < 4; ++nt) {
    biask[nt] = bk[nt * 16 + lrow];
    biasq[nt] = bq[nt * 16 + lrow] * 0.125f;
    biasv[nt] = bv[nt * 16 + lrow];
  }

  // A-fragment of X (fp32 global -> bf16): lane holds X[16t+lrow][kk*32+lgrp*8 .. +7]
  auto xfrag = [&](int tt, int kk) -> s8v {
    const float* p = Xb + (tt * 16 + lrow) * 64 + kk * 32 + lgrp * 8;
    f4v a = *(const f4v*)p;
    f4v b = *(const f4v*)(p + 4);
    s8v f;
    f[0] = (short)f2bf(a[0]); f[1] = (short)f2bf(a[1]);
    f[2] = (short)f2bf(a[2]); f[3] = (short)f2bf(a[3]);
    f[4] = (short)f2bf(b[0]); f[5] = (short)f2bf(b[1]);
    f[6] = (short)f2bf(b[2]); f[7] = (short)f2bf(b[3]);
    return f;
  };

  // ---------- Phase A1: K and V projections for rows [wave*64, wave*64+64) ----------
  {
    s8v wfK[4][2], wfV[4][2];
#pragma unroll
    for (int nt = 0; nt < 4; ++nt)
#pragma unroll
      for (int kk = 0; kk < 2; ++kk) {
        wfK[nt][kk] = *(const s8v*)(WT + (nt * 16 + lrow) * 64 + kk * 32 + lgrp * 8);
        wfV[nt][kk] = *(const s8v*)(WT + 2 * 4096 + (nt * 16 + lrow) * 64 + kk * 32 + lgrp * 8);
      }
#pragma unroll
    for (int it = 0; it < 4; ++it) {
      const int tt = wave * 4 + it;
      const s8v x0 = xfrag(tt, 0);
      const s8v x1 = xfrag(tt, 1);
#pragma unroll
      for (int nt = 0; nt < 4; ++nt) {
        f4v aK = {0.f, 0.f, 0.f, 0.f};
        aK = MFMA16(x0, wfK[nt][0], aK);
        aK = MFMA16(x1, wfK[nt][1], aK);
#pragma unroll
        for (int r = 0; r < 4; ++r) {
          const int row = tt * 16 + lgrp * 4 + r;
          const int off = (row * 128 + (nt * 16 + lrow) * 2) ^ ((row & 7) << 4);
          *(unsigned short*)(Kl + off) = f2bf(aK[r] + biask[nt]);
        }
        f4v aV = {0.f, 0.f, 0.f, 0.f};
        aV = MFMA16(x0, wfV[nt][0], aV);
        aV = MFMA16(x1, wfV[nt][1], aV);
        const int h = nt * 16 + lrow;
        s4v pk;
#pragma unroll
        for (int r = 0; r < 4; ++r) pk[r] = (short)f2bf(aV[r] + biasv[nt]);
        const int offv = (h * 512 + (tt * 16 + lgrp * 4) * 2) ^ ((h & 7) << 4);
        *(s4v*)(Vt + offv) = pk;   // V stored transposed: Vt[h][t]
      }
    }
  }

  // ---------- Phase A2: Q projection for interleaved tiles {wave, wave+4, wave+8, wave+12} ----------
  s8v qf[4][2];   // A-fragments of (scaled) Q, kept in registers
  {
    s8v wfQ[4][2];
#pragma unroll
    for (int nt = 0; nt < 4; ++nt)
#pragma unroll
      for (int kk = 0; kk < 2; ++kk)
        wfQ[nt][kk] = *(const s8v*)(WT + 4096 + (nt * 16 + lrow) * 64 + kk * 32 + lgrp * 8);
#pragma unroll
    for (int i = 0; i < 4; ++i) {
      const int t = wave + i * 4;
      const s8v x0 = xfrag(t, 0);
      const s8v x1 = xfrag(t, 1);
#pragma unroll
      for (int nt = 0; nt < 4; ++nt) {
        f4v a = {0.f, 0.f, 0.f, 0.f};
        a = MFMA16(x0, wfQ[nt][0], a);
        a = MFMA16(x1, wfQ[nt][1], a);
#pragma unroll
        for (int r = 0; r < 4; ++r) {
          const int row = lgrp * 4 + r;   // D layout: row = lgrp*4+r, col = lrow
          const int off = (row * 128 + (nt * 16 + lrow) * 2) ^ ((row & 7) << 4);
          *(unsigned short*)(scw + off) = f2bf(a[r] + biasq[nt]);
        }
      }
      asm volatile("s_waitcnt lgkmcnt(0)" ::: "memory");
      // Re-read in A layout: lane holds Q[lrow][kk*32 + lgrp*8 ..]
      qf[i][0] = *(const s8v*)(scw + ((lrow * 128 + lgrp * 16) ^ ((lrow & 7) << 4)));
      qf[i][1] = *(const s8v*)(scw + ((lrow * 128 + 64 + lgrp * 16) ^ ((lrow & 7) << 4)));
    }
  }

  __syncthreads();   // K/V visible to all waves

  // ---------- Phase B: causal flash attention, per owned Q tile ----------
  for (int i = 0; i < 4; ++i) {
    const int t = wave + i * 4;
    const int nblk = t / 2 + 1;            // KV blocks of 32 needed for rows [16t,16t+16)
    f4v Oa[4];
    float mm[4], ll[4];
#pragma unroll
    for (int nt = 0; nt < 4; ++nt) Oa[nt] = (f4v){0.f, 0.f, 0.f, 0.f};
#pragma unroll
    for (int r = 0; r < 4; ++r) { mm[r] = -1e30f; ll[r] = 0.f; }

    for (int b2 = 0; b2 < nblk; ++b2) {
      f4v S0 = {0.f, 0.f, 0.f, 0.f}, S1 = {0.f, 0.f, 0.f, 0.f};
#pragma unroll
      for (int kk = 0; kk < 2; ++kk) {
        const s8v kf0 = *(const s8v*)(Kl + (((b2 * 32 + lrow) * 128 + kk * 64 + lgrp * 16) ^ ((lrow & 7) << 4)));
        const s8v kf1 = *(const s8v*)(Kl + (((b2 * 32 + 16 + lrow) * 128 + kk * 64 + lgrp * 16) ^ ((lrow & 7) << 4)));
        S0 = MFMA16(qf[i][kk], kf0, S0);
        S1 = MFMA16(qf[i][kk], kf1, S1);
      }
      if (b2 == nblk - 1) {   // diagonal block: causal mask (col > row -> -inf)
#pragma unroll
        for (int r = 0; r < 4; ++r) {
          const int row = t * 16 + lgrp * 4 + r;
          const int c0 = b2 * 32 + lrow;
          if (c0 > row)      S0[r] = -1e30f;
          if (c0 + 16 > row) S1[r] = -1e30f;
        }
      }
      float sc[4];
#pragma unroll
      for (int r = 0; r < 4; ++r) {
        const float pm = redmax16(fmaxf(S0[r], S1[r]));
        const float mn = fmaxf(mm[r], pm);
        sc[r] = exp2f((mm[r] - mn) * 1.44269504f);
        mm[r] = mn;
      }
#pragma unroll
      for (int r = 0; r < 4; ++r) {
        S0[r] = exp2f((S0[r] - mm[r]) * 1.44269504f);
        S1[r] = exp2f((S1[r] - mm[r]) * 1.44269504f);
      }
      // bounce P through per-wave scratch to get the PV A-operand layout
#pragma unroll
      for (int r = 0; r < 4; ++r) {
        const int row = lgrp * 4 + r;
        *(unsigned short*)(scw + ((row * 64 + lrow * 2) ^ ((row & 7) << 4)))      = f2bf(S0[r]);
        *(unsigned short*)(scw + ((row * 64 + 32 + lrow * 2) ^ ((row & 7) << 4))) = f2bf(S1[r]);
      }
#pragma unroll
      for (int r = 0; r < 4; ++r) {
        const float rs = redsum16(S0[r] + S1[r]);
        ll[r] = ll[r] * sc[r] + rs;
      }
#pragma unroll
      for (int nt = 0; nt < 4; ++nt)
#pragma unroll
        for (int r = 0; r < 4; ++r) Oa[nt][r] *= sc[r];
      asm volatile("s_waitcnt lgkmcnt(0)" ::: "memory");
      const s8v pf = *(const s8v*)(scw + ((lrow * 64 + lgrp * 16) ^ ((lrow & 7) << 4)));
#pragma unroll
      for (int nt = 0; nt < 4; ++nt) {
        const s8v vf = *(const s8v*)(Vt + (((nt * 16 + lrow) * 512 + b2 * 64 + lgrp * 16) ^ ((lrow & 7) << 4)));
        Oa[nt] = MFMA16(pf, vf, Oa[nt]);
      }
    }
    float inv[4];
#pragma unroll
    for (int r = 0; r < 4; ++r) inv[r] = 1.0f / ll[r];
#pragma unroll
    for (int nt = 0; nt < 4; ++nt)
#pragma unroll
      for (int r = 0; r < 4; ++r)
        Ob[(t * 16 + lgrp * 4 + r) * 64 + nt * 16 + lrow] = Oa[nt][r] * inv[r];
  }
}

extern "C" void kernel_launch(void* const* d_in, const int* in_sizes, int n_in,
                              void* d_out, int out_size, void* d_ws, size_t ws_size,
                              hipStream_t stream) {
  const float* X  = (const float*)d_in[0];
  const float* Wk = (const float*)d_in[1];
  const float* bk = (const float*)d_in[2];
  const float* Wq = (const float*)d_in[3];
  const float* bq = (const float*)d_in[4];
  const float* Wv = (const float*)d_in[5];
  const float* bv = (const float*)d_in[6];
  float* Out = (float*)d_out;
  unsigned short* WT = (unsigned short*)d_ws;   // 3 * 64*64 bf16 = 24 KB

  const int B = in_sizes[0] / (256 * 64);
  prep_wt<<<dim3(16), dim3(256), 0, stream>>>(Wk, Wq, Wv, WT);
  head_fused<<<dim3(B), dim3(256), 0, stream>>>(X, WT, bk, bq, bv, Out);
}

// Round 3
// 123.088 us; speedup vs baseline: 2.5567x; 2.5567x over previous
//
#include <hip/hip_runtime.h>

typedef short s8v __attribute__((ext_vector_type(8)));
typedef short s4v __attribute__((ext_vector_type(4)));
typedef float f4v __attribute__((ext_vector_type(4)));
typedef unsigned int u32;

#define MFMA16(a,b,c) __builtin_amdgcn_mfma_f32_16x16x32_bf16((a),(b),(c),0,0,0)

__device__ __forceinline__ unsigned short f2bf(float x) {
  union { float f; unsigned u; } v; v.f = x;
  unsigned r = v.u + 0x7FFFu + ((v.u >> 16) & 1u);   // RNE
  return (unsigned short)(r >> 16);
}

__device__ __forceinline__ u32 cvtpk(float lo, float hi) {
  u32 r;
  asm("v_cvt_pk_bf16_f32 %0, %1, %2" : "=v"(r) : "v"(lo), "v"(hi));
  return r;
}

// Weights transposed to bf16: WT[m][n][k] = W_m[k][n].
// Wq pre-scaled by (1/8)*log2(e) so scores are in log2 units (exp2 directly).
__global__ void prep_wt(const float* __restrict__ Wk, const float* __restrict__ Wq,
                        const float* __restrict__ Wv, unsigned short* __restrict__ WT) {
  int i = blockIdx.x * 256 + threadIdx.x;
  if (i >= 64 * 64) return;
  int n = i >> 6, k = i & 63;
  WT[i]            = f2bf(Wk[k * 64 + n]);
  WT[4096 + i]     = f2bf(Wq[k * 64 + n] * (0.125f * 1.44269504f));
  WT[2 * 4096 + i] = f2bf(Wv[k * 64 + n]);
}

// One 512-thread workgroup (8 waves) per batch element.
// LDS: K [256][64] bf16 swz (32K) | V^T [64][256'] bf16 swz (32K), where the key axis
// of V^T is stored PERMUTED within each 32-block (t = 16*hi+4*g+lo -> t' = 8*g+4*hi+lo)
// so that P's natural post-softmax lane layout is directly the PV B-operand (no shuffle).
// Q-bounce scratch is carved from the wave's OWN K region (Q proj runs before K proj).
__global__ __launch_bounds__(512, 4) void head_fused(
    const float* __restrict__ X, const unsigned short* __restrict__ WT,
    const float* __restrict__ bk, const float* __restrict__ bq,
    const float* __restrict__ bv, float* __restrict__ Out)
{
  __shared__ char lds[65536];
  char* Kl = lds;               // byte(row,col) = row*128 + col*2, ^((row&7)<<4)
  char* Vt = lds + 32768;       // byte(h,t')    = h*512  + t'*2,  ^((h&7)<<4)
  const int tid  = threadIdx.x;
  const int wave = tid >> 6;
  const int lane = tid & 63;
  const int lrow = lane & 15;
  const int lgrp = lane >> 4;
  char* scw = Kl + wave * 4096;   // per-wave Q-bounce scratch (own K rows, pre-K-write)

  const float* Xb = X + (size_t)blockIdx.x * (256 * 64);
  float* Ob = Out + (size_t)blockIdx.x * (256 * 64);

  // A-fragment of X (fp32 global -> bf16): lane holds X[16t+lrow][kk*32+lgrp*8 .. +7]
  auto xfrag = [&](int tt, int kk) -> s8v {
    const float* p = Xb + (tt * 16 + lrow) * 64 + kk * 32 + lgrp * 8;
    f4v a = *(const f4v*)p;
    f4v b = *(const f4v*)(p + 4);
    s8v f;
    f[0] = (short)f2bf(a[0]); f[1] = (short)f2bf(a[1]);
    f[2] = (short)f2bf(a[2]); f[3] = (short)f2bf(a[3]);
    f[4] = (short)f2bf(b[0]); f[5] = (short)f2bf(b[1]);
    f[6] = (short)f2bf(b[2]); f[7] = (short)f2bf(b[3]);
    return f;
  };

  // ---------- Phase A2 (first!): Q projection for tiles {wave, 15-wave} ----------
  s8v qf[2][2];   // B-operand fragments of scaled Q (col=lrow=q, k=lgrp*8+j)
  {
    float biasq[4];
#pragma unroll
    for (int nt = 0; nt < 4; ++nt) biasq[nt] = bq[nt * 16 + lrow] * (0.125f * 1.44269504f);
    s8v wfQ[4][2];
#pragma unroll
    for (int nt = 0; nt < 4; ++nt)
#pragma unroll
      for (int kk = 0; kk < 2; ++kk)
        wfQ[nt][kk] = *(const s8v*)(WT + 4096 + (nt * 16 + lrow) * 64 + kk * 32 + lgrp * 8);
#pragma unroll
    for (int i = 0; i < 2; ++i) {
      const int t = i ? (15 - wave) : wave;
      const s8v x0 = xfrag(t, 0);
      const s8v x1 = xfrag(t, 1);
#pragma unroll
      for (int nt = 0; nt < 4; ++nt) {
        f4v a = {0.f, 0.f, 0.f, 0.f};
        a = MFMA16(x0, wfQ[nt][0], a);
        a = MFMA16(x1, wfQ[nt][1], a);
#pragma unroll
        for (int r = 0; r < 4; ++r) {
          const int row = lgrp * 4 + r;   // D layout: row = lgrp*4+r, col = lrow
          const int off = (row * 128 + (nt * 16 + lrow) * 2) ^ ((row & 7) << 4);
          *(unsigned short*)(scw + off) = f2bf(a[r] + biasq[nt]);
        }
      }
      asm volatile("s_waitcnt lgkmcnt(0)" ::: "memory");
      qf[i][0] = *(const s8v*)(scw + ((lrow * 128 + lgrp * 16) ^ ((lrow & 7) << 4)));
      qf[i][1] = *(const s8v*)(scw + ((lrow * 128 + 64 + lgrp * 16) ^ ((lrow & 7) << 4)));
    }
  }

  // ---------- Phase A1: K and V projections for rows [wave*32, wave*32+32) ----------
  {
    float biask[4], biasv[4];
#pragma unroll
    for (int nt = 0; nt < 4; ++nt) {
      biask[nt] = bk[nt * 16 + lrow];
      biasv[nt] = bv[nt * 16 + lrow];
    }
#pragma unroll
    for (int it = 0; it < 2; ++it) {
      const int tt = wave * 2 + it;
      const s8v x0 = xfrag(tt, 0);
      const s8v x1 = xfrag(tt, 1);
#pragma unroll
      for (int nt = 0; nt < 4; ++nt) {
        const s8v wk0 = *(const s8v*)(WT + (nt * 16 + lrow) * 64 + lgrp * 8);
        const s8v wk1 = *(const s8v*)(WT + (nt * 16 + lrow) * 64 + 32 + lgrp * 8);
        const s8v wv0 = *(const s8v*)(WT + 2 * 4096 + (nt * 16 + lrow) * 64 + lgrp * 8);
        const s8v wv1 = *(const s8v*)(WT + 2 * 4096 + (nt * 16 + lrow) * 64 + 32 + lgrp * 8);
        f4v aK = {0.f, 0.f, 0.f, 0.f};
        aK = MFMA16(x0, wk0, aK);
        aK = MFMA16(x1, wk1, aK);
#pragma unroll
        for (int r = 0; r < 4; ++r) {
          const int row = tt * 16 + lgrp * 4 + r;
          const int off = (row * 128 + (nt * 16 + lrow) * 2) ^ ((row & 7) << 4);
          *(unsigned short*)(Kl + off) = f2bf(aK[r] + biask[nt]);
        }
        f4v aV = {0.f, 0.f, 0.f, 0.f};
        aV = MFMA16(x0, wv0, aV);
        aV = MFMA16(x1, wv1, aV);
        const int h = nt * 16 + lrow;
        s4v pk;
#pragma unroll
        for (int r = 0; r < 4; ++r) pk[r] = (short)f2bf(aV[r] + biasv[nt]);
        // permuted key position within 32-block: t=tt*16+lgrp*4+r -> t'=(tt>>1)*32+8*lgrp+4*(tt&1)+r
        const int tp = (tt >> 1) * 32 + 8 * lgrp + 4 * (tt & 1);
        const int offv = (h * 512 + tp * 2) ^ ((h & 7) << 4);
        *(s4v*)(Vt + offv) = pk;   // V stored transposed + key-permuted
      }
    }
  }

  __syncthreads();   // K/V visible to all waves

  // ---------- Phase B: causal flash attention, tiles {wave, 15-wave} (9 blk-iters total) ----------
#pragma unroll
  for (int i = 0; i < 2; ++i) {
    const int t = i ? (15 - wave) : wave;
    const int nblk = (t >> 1) + 1;
    const int qrow = t * 16 + lrow;
    f4v Oa[4];
#pragma unroll
    for (int nt = 0; nt < 4; ++nt) Oa[nt] = (f4v){0.f, 0.f, 0.f, 0.f};
    float mm = -1e30f, ll = 0.f;

    for (int b2 = 0; b2 < nblk; ++b2) {
      f4v S0 = {0.f, 0.f, 0.f, 0.f}, S1 = {0.f, 0.f, 0.f, 0.f};
      __builtin_amdgcn_s_setprio(1);
#pragma unroll
      for (int kk = 0; kk < 2; ++kk) {
        const s8v kf0 = *(const s8v*)(Kl + (((b2 * 32 + lrow) * 128 + kk * 64 + lgrp * 16) ^ ((lrow & 7) << 4)));
        const s8v kf1 = *(const s8v*)(Kl + (((b2 * 32 + 16 + lrow) * 128 + kk * 64 + lgrp * 16) ^ ((lrow & 7) << 4)));
        S0 = MFMA16(kf0, qf[i][kk], S0);   // S^T: row=k, col=q
        S1 = MFMA16(kf1, qf[i][kk], S1);
      }
      __builtin_amdgcn_s_setprio(0);
      if (b2 == nblk - 1) {   // diagonal block: mask k > q
#pragma unroll
        for (int r = 0; r < 4; ++r) {
          const int k0 = b2 * 32 + lgrp * 4 + r;
          if (k0 > qrow)      S0[r] = -1e30f;
          if (k0 + 16 > qrow) S1[r] = -1e30f;
        }
      }
      // online softmax: all 8 scores in-lane are for the same q row (spread over 4 lanes)
      float pm = fmaxf(fmaxf(fmaxf(S0[0], S0[1]), fmaxf(S0[2], S0[3])),
                       fmaxf(fmaxf(S1[0], S1[1]), fmaxf(S1[2], S1[3])));
      pm = fmaxf(pm, __shfl_xor(pm, 16));
      pm = fmaxf(pm, __shfl_xor(pm, 32));
      const float mn = fmaxf(mm, pm);
      const float sc = __builtin_amdgcn_exp2f(mm - mn);
      mm = mn;
#pragma unroll
      for (int r = 0; r < 4; ++r) {
        S0[r] = __builtin_amdgcn_exp2f(S0[r] - mn);
        S1[r] = __builtin_amdgcn_exp2f(S1[r] - mn);
      }
      float rs = ((S0[0] + S0[1]) + (S0[2] + S0[3])) + ((S1[0] + S1[1]) + (S1[2] + S1[3]));
      rs += __shfl_xor(rs, 16);
      rs += __shfl_xor(rs, 32);
      ll = ll * sc + rs;
      // pack P to bf16 — thanks to the permuted V key-axis this IS the PV B-operand
      union { u32 u[4]; s8v v; } pu;
      pu.u[0] = cvtpk(S0[0], S0[1]);
      pu.u[1] = cvtpk(S0[2], S0[3]);
      pu.u[2] = cvtpk(S1[0], S1[1]);
      pu.u[3] = cvtpk(S1[2], S1[3]);
#pragma unroll
      for (int nt = 0; nt < 4; ++nt)
#pragma unroll
        for (int r = 0; r < 4; ++r) Oa[nt][r] *= sc;
      __builtin_amdgcn_s_setprio(1);
#pragma unroll
      for (int nt = 0; nt < 4; ++nt) {
        const s8v vf = *(const s8v*)(Vt + (((nt * 16 + lrow) * 512 + b2 * 64 + lgrp * 16) ^ ((lrow & 7) << 4)));
        Oa[nt] = MFMA16(vf, pu.v, Oa[nt]);   // O^T: row=h, col=q
      }
      __builtin_amdgcn_s_setprio(0);
    }
    const float inv = 1.0f / ll;
#pragma unroll
    for (int nt = 0; nt < 4; ++nt) {
      f4v o;
#pragma unroll
      for (int r = 0; r < 4; ++r) o[r] = Oa[nt][r] * inv;
      *(f4v*)(Ob + (size_t)qrow * 64 + nt * 16 + lgrp * 4) = o;   // 16B vector store
    }
  }
}

extern "C" void kernel_launch(void* const* d_in, const int* in_sizes, int n_in,
                              void* d_out, int out_size, void* d_ws, size_t ws_size,
                              hipStream_t stream) {
  const float* X  = (const float*)d_in[0];
  const float* Wk = (const float*)d_in[1];
  const float* bk = (const float*)d_in[2];
  const float* Wq = (const float*)d_in[3];
  const float* bq = (const float*)d_in[4];
  const float* Wv = (const float*)d_in[5];
  const float* bv = (const float*)d_in[6];
  float* Out = (float*)d_out;
  unsigned short* WT = (unsigned short*)d_ws;   // 3 * 64*64 bf16 = 24 KB

  const int B = in_sizes[0] / (256 * 64);
  prep_wt<<<dim3(16), dim3(256), 0, stream>>>(Wk, Wq, Wv, WT);
  head_fused<<<dim3(B), dim3(512), 0, stream>>>(X, WT, bk, bq, bv, Out);
}